// Round 11
// baseline (1851.700 us; speedup 1.0000x reference)
//
#include <hip/hip_runtime.h>
#include <hip/hip_bf16.h>

#define NU 100000
#define NM 20000
#define DD 64
#define RR 5
#define EE 400000
#define NE (RR * EE)            // 2,000,000 edges per direction
#define NBM (RR * NM)           // 100,000 movie-dst bins (relation-major)
#define NBU (RR * NU)           // 500,000 user-dst bins
#define NBINS (NBM + NBU)
#define NTILE (EE / 16)         // 25,000 16-edge tiles per relation
#define GW_M (NM / 16)          // 1250 movie wave-groups (16 nodes/wave)
#define GW_U (NU / 16)          // 6250 user wave-groups

typedef __attribute__((ext_vector_type(8))) short bf16x8;
typedef __attribute__((ext_vector_type(4))) float f32x4;

static __device__ __forceinline__ short f2bf(float f) {
  return __builtin_bit_cast(short, __float2bfloat16(f));
}

static __device__ __forceinline__ bf16x8 pack8(const float4 a, const float4 b) {
  bf16x8 o;
  o[0] = f2bf(a.x); o[1] = f2bf(a.y); o[2] = f2bf(a.z); o[3] = f2bf(a.w);
  o[4] = f2bf(b.x); o[5] = f2bf(b.y); o[6] = f2bf(b.z); o[7] = f2bf(b.w);
  return o;
}
static __device__ __forceinline__ bf16x8 cvt8(const float* __restrict__ p) {
  return pack8(*(const float4*)p, *(const float4*)(p + 4));
}
static __device__ __forceinline__ bf16x8 pack8v(const float* a) {
  bf16x8 o;
#pragma unroll
  for (int j = 0; j < 8; ++j) o[j] = f2bf(a[j]);
  return o;
}

static __device__ __forceinline__ float sigm(float x) { return 1.f / (1.f + __expf(-x)); }
static __device__ __forceinline__ float gelu(float x) {
  return 0.5f * x * (1.f + erff(x * 0.70710678118654752f));
}

// ---------------------------------------------------------------------------
// rank0: ONE atomic pass over per-(relation,dst) bins.
// Movie bins: r*NM+em  (cnt[0..NBM)), user bins: NBM + r*NU+eu.
// cnt ends up holding per-bin degrees (input to scan2).
// ---------------------------------------------------------------------------
__global__ __launch_bounds__(256) void rank0_k(const int* __restrict__ eu,
                                               const int* __restrict__ em,
                                               int* __restrict__ cnt,
                                               int* __restrict__ rank_m,
                                               int* __restrict__ rank_u) {
  const int i = (blockIdx.x * 256 + threadIdx.x) * 4;
  if (i < NE) {
    const int r = i / EE;                 // EE % 4 == 0: same r for all 4
    int* cm = cnt + r * NM;
    int* cu = cnt + NBM + r * NU;
    const int4 a = *(const int4*)(em + i);
    const int4 b = *(const int4*)(eu + i);
    int4 rm, ru;
    rm.x = atomicAdd(&cm[a.x], 1);
    rm.y = atomicAdd(&cm[a.y], 1);
    rm.z = atomicAdd(&cm[a.z], 1);
    rm.w = atomicAdd(&cm[a.w], 1);
    ru.x = atomicAdd(&cu[b.x], 1);
    ru.y = atomicAdd(&cu[b.y], 1);
    ru.z = atomicAdd(&cu[b.z], 1);
    ru.w = atomicAdd(&cu[b.w], 1);
    *(int4*)(rank_m + i) = rm;
    *(int4*)(rank_u + i) = ru;
  }
}

// ---------------------------------------------------------------------------
// scan2: block 0 scans movie bins (slots [0,NE)), block 1 scans user bins
// (slots [NE,2NE)).  off[NBINS] sentinel = 2*NE.
// ---------------------------------------------------------------------------
__global__ __launch_bounds__(1024) void scan2_k(const int* __restrict__ cnt,
                                                int* __restrict__ off) {
  const int sec  = blockIdx.x;
  const int n    = sec ? NBU : NBM;
  const int base = sec ? NBM : 0;
  const int slot0 = sec ? NE : 0;
  __shared__ int sums[1024];
  const int t = threadIdx.x;
  const int ch = (n + 1023) >> 10;
  const int b0 = t * ch;
  int s = 0;
  for (int i = 0; i < ch; ++i) { int idx = b0 + i; if (idx < n) s += cnt[base + idx]; }
  sums[t] = s;
  __syncthreads();
  for (int d = 1; d < 1024; d <<= 1) {
    int x = (t >= d) ? sums[t - d] : 0;
    __syncthreads();
    sums[t] += x;
    __syncthreads();
  }
  int run = slot0 + ((t > 0) ? sums[t - 1] : 0);
  for (int i = 0; i < ch; ++i) {
    int idx = b0 + i;
    if (idx < n) { off[base + idx] = run; run += cnt[base + idx]; }
  }
  if (sec == 1 && t == 1023) off[NBINS] = NE + sums[1023];   // = 2*NE
}

// ---------------------------------------------------------------------------
// dots: streaming main.  Per 16-edge tile compute the 4 gate dots via one
// MFMA pass (cols: rs_u, ps_u, rs_m, ps_m) and write a 16-B meta record
// (s, w, global_src_row, global_eid) per edge per direction, at the
// destination-sorted slot.  No W gathers, no rotation — deferred to gather.
// ---------------------------------------------------------------------------
__global__ __launch_bounds__(256) void gcmc_dots(
    const int* __restrict__ edges_u, const int* __restrict__ edges_m,
    const float* __restrict__ rfeat,
    const float* __restrict__ ps_u, const float* __restrict__ rs_u,
    const float* __restrict__ ps_m, const float* __restrict__ rs_m,
    const float* __restrict__ user_cj, const float* __restrict__ movie_cj,
    const int* __restrict__ rank_m, const int* __restrict__ rank_u,
    const int* __restrict__ off,
    float4* __restrict__ meta)
{
  const int r    = blockIdx.y;
  const int lane = threadIdx.x & 63;
  const int wid  = threadIdx.x >> 6;
  const int c    = lane & 15;
  const int kr   = lane >> 4;
  const int wtile = blockIdx.x * 4 + wid;
  if (wtile >= NTILE / 8) return;

  // Bs: cols 0-3 = rs_u, ps_u, rs_m, ps_m (others zero)
  bf16x8 Bs[2];
#pragma unroll
  for (int s = 0; s < 2; ++s) {
    if (c < 4) {
      const float* v = (c == 0 ? rs_u : c == 1 ? ps_u : c == 2 ? rs_m : ps_m)
                       + r * DD + s * 32 + kr * 8;
      Bs[s] = cvt8(v);
    } else {
      bf16x8 z = {0, 0, 0, 0, 0, 0, 0, 0};
      Bs[s] = z;
    }
  }

#pragma unroll 1
  for (int tt = 0; tt < 8; ++tt) {
    const int tile = wtile * 8 + tt;
    const int e0 = tile * 16;

    const float* arow = rfeat + ((size_t)r * EE + e0 + c) * DD + kr * 8;
    const bf16x8 A0 = cvt8(arow);
    const bf16x8 A1 = cvt8(arow + 32);

    const int ebase = r * EE + e0 + kr * 4;
    const int4 eu4  = *(const int4*)(edges_u + ebase);
    const int4 em4  = *(const int4*)(edges_m + ebase);
    const int4 rm4  = *(const int4*)(rank_m + ebase);
    const int4 ru4  = *(const int4*)(rank_u + ebase);
    const int eus[4] = {eu4.x, eu4.y, eu4.z, eu4.w};
    const int ems[4] = {em4.x, em4.y, em4.z, em4.w};
    const int rms[4] = {rm4.x, rm4.y, rm4.z, rm4.w};
    const int rus[4] = {ru4.x, ru4.y, ru4.z, ru4.w};

    f32x4 Cs = {0.f, 0.f, 0.f, 0.f};
    Cs = __builtin_amdgcn_mfma_f32_16x16x32_bf16(A0, Bs[0], Cs, 0, 0, 0);
    Cs = __builtin_amdgcn_mfma_f32_16x16x32_bf16(A1, Bs[1], Cs, 0, 0, 0);

#pragma unroll
    for (int q = 0; q < 4; ++q) {
      const int src = (lane & 48);
      const float su = __shfl(Cs[q], src);       // rfeat . rs_u
      const float pu = __shfl(Cs[q], src | 1);   // rfeat . ps_u
      const float sm = __shfl(Cs[q], src | 2);   // rfeat . rs_m
      const float pm = __shfl(Cs[q], src | 3);   // rfeat . ps_m
      if (c == 0) {
        const int eu_ = eus[q], em_ = ems[q];
        const float cju = user_cj[eu_];
        const float cjm = movie_cj[em_];
        const int slm = off[r * NM + em_] + rms[q];
        const int slu = off[NBM + r * NU + eu_] + rus[q];
        const int eg  = r * EE + e0 + kr * 4 + q;   // global edge id
        float4 mm, mu;
        mm.x = sigm(su) * cju;                       // s (rf-term weight)
        mm.y = sigm(pu) * cju;                       // w (W-term weight)
        mm.z = __builtin_bit_cast(float, r * NU + eu_);
        mm.w = __builtin_bit_cast(float, eg);
        mu.x = sigm(sm) * cjm;
        mu.y = sigm(pm) * cjm;
        mu.z = __builtin_bit_cast(float, r * NM + em_);
        mu.w = __builtin_bit_cast(float, eg);
        meta[slm] = mm;
        meta[slu] = mu;
      }
    }
  }
}

// ---------------------------------------------------------------------------
// gather+rotate: one wave per 16 destination nodes.  Per relation r:
// accumulate acc = SUM s_e*rfeat_e and accW = SUM w_e*W_src[src_e] in fp32
// (lane (c,kr) holds node c, dims kr*8..+8 and 32+kr*8..+8), then one MFMA
// pass rotates acc by rw_r.T and passes accW through via identity-B fragments
// (B[k][4c+t] = (k==4c+t)), accumulating all relations into C.
// ---------------------------------------------------------------------------
__global__ __launch_bounds__(256) void gather_rot_k(
    const int* __restrict__ off, const float4* __restrict__ meta,
    const float* __restrict__ rfeat,
    const float* __restrict__ W_user, const float* __restrict__ W_movie,
    const float* __restrict__ rw_u, const float* __restrict__ rw_m,
    float* __restrict__ out)
{
  const int wg   = blockIdx.x * 4 + (threadIdx.x >> 6);
  const int lane = threadIdx.x & 63;
  const int c    = lane & 15;
  const int kr   = lane >> 4;
  const bool isM = (wg < GW_M);
  const int nbase = isM ? wg * 16 : (wg - GW_M) * 16;
  const float* W  = isM ? W_user : W_movie;   // movie_agg gathers W_user rows
  const float* rw = isM ? rw_u : rw_m;        // movie_agg rotates by rw_u
  float* obase    = isM ? (out + (size_t)NU * DD) : out;

  // identity-B fragments: element j of IB[t][s] is 1.0bf16 iff
  // k = s*32+kr*8+j equals output dim 4c+t.
  bf16x8 IB[4][2];
#pragma unroll
  for (int t = 0; t < 4; ++t) {
#pragma unroll
    for (int s = 0; s < 2; ++s) {
      bf16x8 z;
#pragma unroll
      for (int j = 0; j < 8; ++j)
        z[j] = (4 * c + t == s * 32 + kr * 8 + j) ? (short)0x3F80 : (short)0;
      IB[t][s] = z;
    }
  }

  f32x4 C[4];
#pragma unroll
  for (int t = 0; t < 4; ++t) { f32x4 z4 = {0.f,0.f,0.f,0.f}; C[t] = z4; }

#pragma unroll 1
  for (int r = 0; r < RR; ++r) {
    // rotation B fragments: B[k][col c, tile t] = rw[r][4c+t][k]
    bf16x8 B[4][2];
#pragma unroll
    for (int t = 0; t < 4; ++t)
#pragma unroll
      for (int s = 0; s < 2; ++s)
        B[t][s] = cvt8(rw + ((size_t)r * DD + (4 * c + t)) * DD + s * 32 + kr * 8);

    const int bin = isM ? (r * NM + nbase + c) : (NBM + r * NU + nbase + c);
    const int s0 = off[bin];
    const int e1 = off[bin + 1];

    float acc0[8] = {0,0,0,0,0,0,0,0};
    float acc1[8] = {0,0,0,0,0,0,0,0};
    float aw0[8]  = {0,0,0,0,0,0,0,0};
    float aw1[8]  = {0,0,0,0,0,0,0,0};

    for (int k = s0; k < e1; ++k) {
      const float4 md = meta[k];
      const int src = __builtin_bit_cast(int, md.z);
      const int eid = __builtin_bit_cast(int, md.w);
      const float s = md.x;
      const float w = md.y;
      const float* rr = rfeat + (size_t)eid * DD + kr * 8;
      const float4 f0 = *(const float4*)(rr);
      const float4 f1 = *(const float4*)(rr + 4);
      const float4 f2 = *(const float4*)(rr + 32);
      const float4 f3 = *(const float4*)(rr + 36);
      const float* wr = W + (size_t)src * DD + kr * 8;
      const float4 g0 = *(const float4*)(wr);
      const float4 g1 = *(const float4*)(wr + 4);
      const float4 g2 = *(const float4*)(wr + 32);
      const float4 g3 = *(const float4*)(wr + 36);
      acc0[0] += s * f0.x; acc0[1] += s * f0.y; acc0[2] += s * f0.z; acc0[3] += s * f0.w;
      acc0[4] += s * f1.x; acc0[5] += s * f1.y; acc0[6] += s * f1.z; acc0[7] += s * f1.w;
      acc1[0] += s * f2.x; acc1[1] += s * f2.y; acc1[2] += s * f2.z; acc1[3] += s * f2.w;
      acc1[4] += s * f3.x; acc1[5] += s * f3.y; acc1[6] += s * f3.z; acc1[7] += s * f3.w;
      aw0[0] += w * g0.x; aw0[1] += w * g0.y; aw0[2] += w * g0.z; aw0[3] += w * g0.w;
      aw0[4] += w * g1.x; aw0[5] += w * g1.y; aw0[6] += w * g1.z; aw0[7] += w * g1.w;
      aw1[0] += w * g2.x; aw1[1] += w * g2.y; aw1[2] += w * g2.z; aw1[3] += w * g2.w;
      aw1[4] += w * g3.x; aw1[5] += w * g3.y; aw1[6] += w * g3.z; aw1[7] += w * g3.w;
    }

    const bf16x8 A0 = pack8v(acc0);
    const bf16x8 A1 = pack8v(acc1);
    const bf16x8 V0 = pack8v(aw0);
    const bf16x8 V1 = pack8v(aw1);
#pragma unroll
    for (int t = 0; t < 4; ++t) {
      C[t] = __builtin_amdgcn_mfma_f32_16x16x32_bf16(A0, B[t][0], C[t], 0, 0, 0);
      C[t] = __builtin_amdgcn_mfma_f32_16x16x32_bf16(A1, B[t][1], C[t], 0, 0, 0);
      C[t] = __builtin_amdgcn_mfma_f32_16x16x32_bf16(V0, IB[t][0], C[t], 0, 0, 0);
      C[t] = __builtin_amdgcn_mfma_f32_16x16x32_bf16(V1, IB[t][1], C[t], 0, 0, 0);
    }
  }

  // C layout: col = lane&15 -> dim group 4c+t ; row = kr*4+q -> node
#pragma unroll
  for (int q = 0; q < 4; ++q) {
    const int node = nbase + kr * 4 + q;
    float4 o;
    o.x = C[0][q]; o.y = C[1][q]; o.z = C[2][q]; o.w = C[3][q];
    *(float4*)(obase + (size_t)node * DD + 4 * c) = o;
  }
}

// ---------------------------------------------------------------------------
// FC kernel (in-place on d_out): row -> gelu(row*ci) @ W.T + b, 16 rows/wave.
// ---------------------------------------------------------------------------
__global__ __launch_bounds__(256) void gcmc_fc(
    float* __restrict__ out,
    const float* __restrict__ user_ci, const float* __restrict__ movie_ci,
    const float* __restrict__ ufc_w, const float* __restrict__ ufc_b,
    const float* __restrict__ ifc_w, const float* __restrict__ ifc_b)
{
  const int wt   = blockIdx.x * 4 + (threadIdx.x >> 6);
  const int lane = threadIdx.x & 63;
  const int c    = lane & 15;
  const int kr   = lane >> 4;
  const bool isU = wt < (NU / 16);
  float* base        = isU ? out : out + (size_t)NU * DD;
  const float* ci    = isU ? user_ci : movie_ci;
  const float* W     = isU ? ufc_w : ifc_w;
  const float* bias  = isU ? ufc_b : ifc_b;
  const int row0 = (isU ? wt : wt - (NU / 16)) * 16;

  bf16x8 B[4][2];
#pragma unroll
  for (int t = 0; t < 4; ++t)
#pragma unroll
    for (int s = 0; s < 2; ++s)
      B[t][s] = cvt8(W + (size_t)(4 * c + t) * DD + s * 32 + kr * 8);

  const float civ = ci[row0 + c];
  const float* arow = base + (size_t)(row0 + c) * DD + kr * 8;

  bf16x8 A0, A1;
  {
    const float4 a = *(const float4*)arow;
    const float4 b = *(const float4*)(arow + 4);
    const float4 a2 = *(const float4*)(arow + 32);
    const float4 b2 = *(const float4*)(arow + 36);
    A0[0] = f2bf(gelu(a.x * civ));  A0[1] = f2bf(gelu(a.y * civ));
    A0[2] = f2bf(gelu(a.z * civ));  A0[3] = f2bf(gelu(a.w * civ));
    A0[4] = f2bf(gelu(b.x * civ));  A0[5] = f2bf(gelu(b.y * civ));
    A0[6] = f2bf(gelu(b.z * civ));  A0[7] = f2bf(gelu(b.w * civ));
    A1[0] = f2bf(gelu(a2.x * civ)); A1[1] = f2bf(gelu(a2.y * civ));
    A1[2] = f2bf(gelu(a2.z * civ)); A1[3] = f2bf(gelu(a2.w * civ));
    A1[4] = f2bf(gelu(b2.x * civ)); A1[5] = f2bf(gelu(b2.y * civ));
    A1[6] = f2bf(gelu(b2.z * civ)); A1[7] = f2bf(gelu(b2.w * civ));
  }

  f32x4 z4 = {0.f, 0.f, 0.f, 0.f};
  f32x4 C[4];
#pragma unroll
  for (int t = 0; t < 4; ++t) {
    C[t] = z4;
    C[t] = __builtin_amdgcn_mfma_f32_16x16x32_bf16(A0, B[t][0], C[t], 0, 0, 0);
    C[t] = __builtin_amdgcn_mfma_f32_16x16x32_bf16(A1, B[t][1], C[t], 0, 0, 0);
  }

  const float4 b4 = *(const float4*)(bias + 4 * c);
#pragma unroll
  for (int q = 0; q < 4; ++q) {
    const int row = row0 + kr * 4 + q;
    float4 o;
    o.x = C[0][q] + b4.x; o.y = C[1][q] + b4.y;
    o.z = C[2][q] + b4.z; o.w = C[3][q] + b4.w;
    *(float4*)(base + (size_t)row * DD + 4 * c) = o;
  }
}

extern "C" void kernel_launch(void* const* d_in, const int* in_sizes, int n_in,
                              void* d_out, int out_size, void* d_ws, size_t ws_size,
                              hipStream_t stream) {
  const int*   edges_u  = (const int*)  d_in[0];
  const int*   edges_m  = (const int*)  d_in[1];
  const float* rfeat    = (const float*)d_in[2];
  const float* W_user   = (const float*)d_in[3];
  const float* W_movie  = (const float*)d_in[4];
  const float* ps_u     = (const float*)d_in[5];
  const float* rs_u     = (const float*)d_in[6];
  const float* rw_u     = (const float*)d_in[7];
  const float* ps_m     = (const float*)d_in[8];
  const float* rs_m     = (const float*)d_in[9];
  const float* rw_m     = (const float*)d_in[10];
  const float* user_cj  = (const float*)d_in[11];
  const float* user_ci  = (const float*)d_in[12];
  const float* movie_cj = (const float*)d_in[13];
  const float* movie_ci = (const float*)d_in[14];
  const float* ufc_w    = (const float*)d_in[15];
  const float* ufc_b    = (const float*)d_in[16];
  const float* ifc_w    = (const float*)d_in[17];
  const float* ifc_b    = (const float*)d_in[18];

  float* out = (float*)d_out;

  // ---- workspace layout (~85 MB) ----
  char* ws = (char*)d_ws;
  size_t o = 0;
  auto alloc = [&](size_t bytes) { char* p = ws + o; o += (bytes + 255) & ~(size_t)255; return p; };
  int*    cnt    = (int*)   alloc(sizeof(int) * NBINS);
  int*    off    = (int*)   alloc(sizeof(int) * (NBINS + 1));
  int*    rank_m = (int*)   alloc(sizeof(int) * NE);
  int*    rank_u = (int*)   alloc(sizeof(int) * NE);
  float4* meta   = (float4*)alloc(sizeof(float4) * (size_t)2 * NE);   // 64 MB
  (void)ws_size;

  hipMemsetAsync(cnt, 0, sizeof(int) * NBINS, stream);
  rank0_k<<<(NE / 4 + 255) / 256, 256, 0, stream>>>(edges_u, edges_m, cnt, rank_m, rank_u);
  scan2_k<<<2, 1024, 0, stream>>>(cnt, off);

  dim3 g1((NTILE / 8 + 3) / 4, RR);   // (782, 5)
  gcmc_dots<<<g1, 256, 0, stream>>>(edges_u, edges_m, rfeat,
                                    ps_u, rs_u, ps_m, rs_m,
                                    user_cj, movie_cj, rank_m, rank_u, off, meta);

  gather_rot_k<<<(GW_M + GW_U) / 4, 256, 0, stream>>>(off, meta, rfeat,
                                                      W_user, W_movie, rw_u, rw_m, out);

  gcmc_fc<<<((NU + NM) / 16) / 4, 256, 0, stream>>>(out, user_ci, movie_ci,
                                                    ufc_w, ufc_b, ifc_w, ifc_b);
}

// Round 12
// 702.459 us; speedup vs baseline: 2.6360x; 2.6360x over previous
//
#include <hip/hip_runtime.h>
#include <hip/hip_bf16.h>

#define NU 100000
#define NM 20000
#define DD 64
#define RR 5
#define EE 400000
#define NE (RR * EE)            // 2,000,000 edges per direction
#define NNODE (NM + NU)         // 120,000 destination bins (movies first)
#define NTILE (EE / 16)         // 25,000 16-edge tiles per relation
#define NCHUNK ((NNODE + 1023) / 1024)   // 118 scan chunks
#define GM_BLOCKS (NM / 4)      // 5000 movie-gather blocks (4 movies/block)
#define GU_BLOCKS (NU / 32)     // 3125 user-gather blocks (32 users/block)

typedef __attribute__((ext_vector_type(8))) short bf16x8;
typedef __attribute__((ext_vector_type(8))) short s16x8;
typedef __attribute__((ext_vector_type(4))) float f32x4;

static __device__ __forceinline__ short f2bf(float f) {
  return __builtin_bit_cast(short, __float2bfloat16(f));
}
static __device__ __forceinline__ float bf2f(short s) {
  return __builtin_bit_cast(float, ((unsigned)(unsigned short)s) << 16);
}

static __device__ __forceinline__ bf16x8 pack8(const float4 a, const float4 b) {
  bf16x8 o;
  o[0] = f2bf(a.x); o[1] = f2bf(a.y); o[2] = f2bf(a.z); o[3] = f2bf(a.w);
  o[4] = f2bf(b.x); o[5] = f2bf(b.y); o[6] = f2bf(b.z); o[7] = f2bf(b.w);
  return o;
}
static __device__ __forceinline__ bf16x8 cvt8(const float* __restrict__ p) {
  return pack8(*(const float4*)p, *(const float4*)(p + 4));
}

static __device__ __forceinline__ float sigm(float x) { return 1.f / (1.f + __expf(-x)); }
static __device__ __forceinline__ float gelu(float x) {
  return 0.5f * x * (1.f + erff(x * 0.70710678118654752f));
}

// ---------------------------------------------------------------------------
// rank0: ONE atomic pass. cnt (zeroed) -> per-edge rank within destination,
// and cnt ends up holding the per-node degree (input to the scan).
// ---------------------------------------------------------------------------
__global__ __launch_bounds__(256) void rank0_k(const int* __restrict__ eu,
                                               const int* __restrict__ em,
                                               int* __restrict__ cnt,
                                               int* __restrict__ rank_m,
                                               int* __restrict__ rank_u) {
  const int i = (blockIdx.x * 256 + threadIdx.x) * 4;
  if (i < NE) {
    const int4 a = *(const int4*)(em + i);
    const int4 b = *(const int4*)(eu + i);
    int4 rm, ru;
    rm.x = atomicAdd(&cnt[a.x], 1);
    rm.y = atomicAdd(&cnt[a.y], 1);
    rm.z = atomicAdd(&cnt[a.z], 1);
    rm.w = atomicAdd(&cnt[a.w], 1);
    ru.x = atomicAdd(&cnt[NM + b.x], 1);
    ru.y = atomicAdd(&cnt[NM + b.y], 1);
    ru.z = atomicAdd(&cnt[NM + b.z], 1);
    ru.w = atomicAdd(&cnt[NM + b.w], 1);
    *(int4*)(rank_m + i) = rm;
    *(int4*)(rank_u + i) = ru;
  }
}

// ---------------------------------------------------------------------------
// 3-phase parallel exclusive scan over cnt[NNODE] -> off (R11 lesson: the
// serial 1-block scan was ~250-1000us latency-bound; this is ~30us total).
// ---------------------------------------------------------------------------
__global__ __launch_bounds__(256) void scan_p1(const int* __restrict__ cnt,
                                               int* __restrict__ bsum) {
  const int b = blockIdx.x;
  const int t = threadIdx.x;
  const int idx = b * 1024 + t * 4;
  int s = 0;
  if (idx + 3 < NNODE) {
    const int4 v = *(const int4*)(cnt + idx);
    s = v.x + v.y + v.z + v.w;
  } else {
    for (int j = 0; j < 4; ++j) if (idx + j < NNODE) s += cnt[idx + j];
  }
  __shared__ int red[4];
  for (int d = 1; d < 64; d <<= 1) s += __shfl_xor(s, d);
  if ((t & 63) == 0) red[t >> 6] = s;
  __syncthreads();
  if (t == 0) bsum[b] = red[0] + red[1] + red[2] + red[3];
}

__global__ __launch_bounds__(1024) void scan_p2(const int* __restrict__ bsum,
                                                int* __restrict__ bpre) {
  __shared__ int sh[1024];
  const int t = threadIdx.x;
  const int v = (t < NCHUNK) ? bsum[t] : 0;
  sh[t] = v;
  __syncthreads();
  for (int d = 1; d < 1024; d <<= 1) {
    const int x = (t >= d) ? sh[t - d] : 0;
    __syncthreads();
    sh[t] += x;
    __syncthreads();
  }
  if (t < NCHUNK) bpre[t] = sh[t] - v;   // exclusive block prefix
}

__global__ __launch_bounds__(256) void scan_p3(const int* __restrict__ cnt,
                                               const int* __restrict__ bpre,
                                               int* __restrict__ off) {
  const int b = blockIdx.x;
  const int t = threadIdx.x;
  const int idx = b * 1024 + t * 4;
  int4 v = {0, 0, 0, 0};
  if (idx + 3 < NNODE) v = *(const int4*)(cnt + idx);
  else {
    if (idx     < NNODE) v.x = cnt[idx];
    if (idx + 1 < NNODE) v.y = cnt[idx + 1];
    if (idx + 2 < NNODE) v.z = cnt[idx + 2];
    if (idx + 3 < NNODE) v.w = cnt[idx + 3];
  }
  const int s = v.x + v.y + v.z + v.w;
  __shared__ int sh[256];
  sh[t] = s;
  __syncthreads();
  for (int d = 1; d < 256; d <<= 1) {
    const int x = (t >= d) ? sh[t - d] : 0;
    __syncthreads();
    sh[t] += x;
    __syncthreads();
  }
  const int pre = bpre[b] + sh[t] - s;
  int4 o;
  o.x = pre;
  o.y = pre + v.x;
  o.z = pre + v.x + v.y;
  o.w = pre + v.x + v.y + v.z;
  if (idx + 3 < NNODE) *(int4*)(off + idx) = o;
  else {
    if (idx     < NNODE) off[idx]     = o.x;
    if (idx + 1 < NNODE) off[idx + 1] = o.y;
    if (idx + 2 < NNODE) off[idx + 2] = o.z;
    if (idx + 3 < NNODE) off[idx + 3] = o.w;
  }
  if (b == 0 && t == 0) off[NNODE] = 2 * NE;
}

// ---------------------------------------------------------------------------
// Main fused MFMA kernel — flat schedule, single dispatch (best measured).
// Per 16-edge tile: both directions' messages via one MFMA pass, stored (bf16)
// at slot = off[dst] + rank.  Column permutation: tile t, col c -> dim 4c+t.
// NOTE: no min-waves clamp — VGPR ~108 is what this kernel needs (R9 lesson:
// forcing VGPR 48 -> scratch spills -> FETCH 2.7x).
// ---------------------------------------------------------------------------
__global__ __launch_bounds__(256) void gcmc_main(
    const int* __restrict__ edges_u, const int* __restrict__ edges_m,
    const float* __restrict__ rfeat,
    const float* __restrict__ W_user, const float* __restrict__ W_movie,
    const float* __restrict__ ps_u, const float* __restrict__ rs_u, const float* __restrict__ rw_u,
    const float* __restrict__ ps_m, const float* __restrict__ rs_m, const float* __restrict__ rw_m,
    const float* __restrict__ user_cj, const float* __restrict__ movie_cj,
    const int* __restrict__ rank_m, const int* __restrict__ rank_u,
    const int* __restrict__ off,
    short* __restrict__ msg)
{
  const int r    = blockIdx.y;
  const int lane = threadIdx.x & 63;
  const int wid  = threadIdx.x >> 6;
  const int c    = lane & 15;
  const int kr   = lane >> 4;
  const int wtile = blockIdx.x * 4 + wid;
  if (wtile >= NTILE / 8) return;

  bf16x8 Bu[4][2], Bm[4][2], Bs[2];
#pragma unroll
  for (int t = 0; t < 4; ++t) {
#pragma unroll
    for (int s = 0; s < 2; ++s) {
      Bu[t][s] = cvt8(rw_u + ((size_t)r * DD + (4 * c + t)) * DD + s * 32 + kr * 8);
      Bm[t][s] = cvt8(rw_m + ((size_t)r * DD + (4 * c + t)) * DD + s * 32 + kr * 8);
    }
  }
#pragma unroll
  for (int s = 0; s < 2; ++s) {
    if (c < 4) {
      const float* v = (c == 0 ? rs_u : c == 1 ? ps_u : c == 2 ? rs_m : ps_m)
                       + r * DD + s * 32 + kr * 8;
      Bs[s] = cvt8(v);
    } else {
      bf16x8 z = {0, 0, 0, 0, 0, 0, 0, 0};
      Bs[s] = z;
    }
  }

#pragma unroll 1
  for (int tt = 0; tt < 8; ++tt) {
    const int tile = wtile * 8 + tt;
    const int e0 = tile * 16;

    const float* arow = rfeat + ((size_t)r * EE + e0 + c) * DD + kr * 8;
    const float4 fa0 = *(const float4*)arow;
    const float4 fa1 = *(const float4*)(arow + 4);
    const float4 fa2 = *(const float4*)(arow + 32);
    const float4 fa3 = *(const float4*)(arow + 36);

    const int ebase = r * EE + e0 + kr * 4;
    const int4 eu4  = *(const int4*)(edges_u + ebase);
    const int4 em4  = *(const int4*)(edges_m + ebase);
    const int4 rm4  = *(const int4*)(rank_m + ebase);
    const int4 ru4  = *(const int4*)(rank_u + ebase);
    const int eus[4] = {eu4.x, eu4.y, eu4.z, eu4.w};
    const int ems[4] = {em4.x, em4.y, em4.z, em4.w};
    const int rms[4] = {rm4.x, rm4.y, rm4.z, rm4.w};
    const int rus[4] = {ru4.x, ru4.y, ru4.z, ru4.w};

    int slm[4], slu[4];
    float cju[4], cjm[4];
    float4 hu[4], hm[4];
#pragma unroll
    for (int q = 0; q < 4; ++q) {
      slm[q] = off[ems[q]] + rms[q];
      slu[q] = off[NM + eus[q]] + rus[q];
      cju[q] = user_cj[eus[q]];
      cjm[q] = movie_cj[ems[q]];
      hu[q]  = *(const float4*)(W_user  + ((size_t)r * NU + eus[q]) * DD + 4 * c);
      hm[q]  = *(const float4*)(W_movie + ((size_t)r * NM + ems[q]) * DD + 4 * c);
    }

    const bf16x8 A0 = pack8(fa0, fa1);
    const bf16x8 A1 = pack8(fa2, fa3);
    f32x4 z4 = {0.f, 0.f, 0.f, 0.f};
    f32x4 Cu[4], Cm[4], Cs;
#pragma unroll
    for (int t = 0; t < 4; ++t) { Cu[t] = z4; Cm[t] = z4; }
    Cs = z4;
#pragma unroll
    for (int t = 0; t < 4; ++t) {
      Cu[t] = __builtin_amdgcn_mfma_f32_16x16x32_bf16(A0, Bu[t][0], Cu[t], 0, 0, 0);
      Cu[t] = __builtin_amdgcn_mfma_f32_16x16x32_bf16(A1, Bu[t][1], Cu[t], 0, 0, 0);
      Cm[t] = __builtin_amdgcn_mfma_f32_16x16x32_bf16(A0, Bm[t][0], Cm[t], 0, 0, 0);
      Cm[t] = __builtin_amdgcn_mfma_f32_16x16x32_bf16(A1, Bm[t][1], Cm[t], 0, 0, 0);
    }
    Cs = __builtin_amdgcn_mfma_f32_16x16x32_bf16(A0, Bs[0], Cs, 0, 0, 0);
    Cs = __builtin_amdgcn_mfma_f32_16x16x32_bf16(A1, Bs[1], Cs, 0, 0, 0);

#pragma unroll
    for (int q = 0; q < 4; ++q) {
      const int src = (lane & 48);
      const float su = __shfl(Cs[q], src);
      const float pu = __shfl(Cs[q], src | 1);
      const float sm = __shfl(Cs[q], src | 2);
      const float pm = __shfl(Cs[q], src | 3);
      const float sgu = sigm(su), pau = sigm(pu);
      const float sgm_ = sigm(sm), pam = sigm(pm);

      short4 vm, vu;
      vm.x = f2bf((hu[q].x * pau + Cu[0][q] * sgu) * cju[q]);
      vm.y = f2bf((hu[q].y * pau + Cu[1][q] * sgu) * cju[q]);
      vm.z = f2bf((hu[q].z * pau + Cu[2][q] * sgu) * cju[q]);
      vm.w = f2bf((hu[q].w * pau + Cu[3][q] * sgu) * cju[q]);
      vu.x = f2bf((hm[q].x * pam + Cm[0][q] * sgm_) * cjm[q]);
      vu.y = f2bf((hm[q].y * pam + Cm[1][q] * sgm_) * cjm[q]);
      vu.z = f2bf((hm[q].z * pam + Cm[2][q] * sgm_) * cjm[q]);
      vu.w = f2bf((hm[q].w * pam + Cm[3][q] * sgm_) * cjm[q]);

      *(short4*)(msg + ((size_t)slm[q] << 6) + 4 * c) = vm;
      *(short4*)(msg + ((size_t)slu[q] << 6) + 4 * c) = vu;
    }
  }
}

// ---------------------------------------------------------------------------
// Merged gather-reduce (one dispatch).
//  blocks [0, GM_BLOCKS): movies — one wave per movie, 8 rows/instr, 4-deep.
//  blocks [GM_BLOCKS, +GU_BLOCKS): users — 8 lanes/user, 32 users/block, 4-deep.
// ---------------------------------------------------------------------------
__global__ __launch_bounds__(256) void gather_k(const int* __restrict__ off,
                                                const short* __restrict__ msg,
                                                float* __restrict__ out)
{
  if (blockIdx.x < GM_BLOCKS) {
    const int w    = blockIdx.x * 4 + (threadIdx.x >> 6);   // movie id
    const int lane = threadIdx.x & 63;
    const int sub  = lane >> 3;    // row group 0..7
    const int c8   = lane & 7;     // 16-byte chunk

    const int s0 = off[w];
    const int e1 = off[w + 1];

    float a0[8] = {0,0,0,0,0,0,0,0};
    float a1[8] = {0,0,0,0,0,0,0,0};
    float a2[8] = {0,0,0,0,0,0,0,0};
    float a3[8] = {0,0,0,0,0,0,0,0};
    int k = s0 + sub;
    for (; k + 24 < e1; k += 32) {
      const s16x8 v0 = *(const s16x8*)(msg + ((size_t)k << 6) + 8 * c8);
      const s16x8 v1 = *(const s16x8*)(msg + ((size_t)(k + 8) << 6) + 8 * c8);
      const s16x8 v2 = *(const s16x8*)(msg + ((size_t)(k + 16) << 6) + 8 * c8);
      const s16x8 v3 = *(const s16x8*)(msg + ((size_t)(k + 24) << 6) + 8 * c8);
#pragma unroll
      for (int j = 0; j < 8; ++j) {
        a0[j] += bf2f(v0[j]); a1[j] += bf2f(v1[j]);
        a2[j] += bf2f(v2[j]); a3[j] += bf2f(v3[j]);
      }
    }
    for (; k < e1; k += 8) {
      const s16x8 v0 = *(const s16x8*)(msg + ((size_t)k << 6) + 8 * c8);
#pragma unroll
      for (int j = 0; j < 8; ++j) a0[j] += bf2f(v0[j]);
    }
#pragma unroll
    for (int j = 0; j < 8; ++j) {
      a0[j] += a1[j] + a2[j] + a3[j];
      a0[j] += __shfl_xor(a0[j], 8);
      a0[j] += __shfl_xor(a0[j], 16);
      a0[j] += __shfl_xor(a0[j], 32);
    }
    if (sub == 0) {
      float* dst = out + (size_t)NU * DD + (size_t)w * DD + 8 * c8;
      float4 o0 = {a0[0], a0[1], a0[2], a0[3]};
      float4 o1 = {a0[4], a0[5], a0[6], a0[7]};
      *(float4*)dst = o0;
      *(float4*)(dst + 4) = o1;
    }
  } else {
    const int u  = (blockIdx.x - GM_BLOCKS) * 32 + (threadIdx.x >> 3);   // user id
    const int c8 = threadIdx.x & 7;

    const int s0 = off[NM + u];
    const int e1 = off[NM + u + 1];

    float a0[8] = {0,0,0,0,0,0,0,0};
    float a1[8] = {0,0,0,0,0,0,0,0};
    float a2[8] = {0,0,0,0,0,0,0,0};
    float a3[8] = {0,0,0,0,0,0,0,0};
    int k = s0;
    for (; k + 3 < e1; k += 4) {
      const s16x8 v0 = *(const s16x8*)(msg + ((size_t)k << 6) + 8 * c8);
      const s16x8 v1 = *(const s16x8*)(msg + ((size_t)(k + 1) << 6) + 8 * c8);
      const s16x8 v2 = *(const s16x8*)(msg + ((size_t)(k + 2) << 6) + 8 * c8);
      const s16x8 v3 = *(const s16x8*)(msg + ((size_t)(k + 3) << 6) + 8 * c8);
#pragma unroll
      for (int j = 0; j < 8; ++j) {
        a0[j] += bf2f(v0[j]); a1[j] += bf2f(v1[j]);
        a2[j] += bf2f(v2[j]); a3[j] += bf2f(v3[j]);
      }
    }
    for (; k < e1; ++k) {
      const s16x8 v0 = *(const s16x8*)(msg + ((size_t)k << 6) + 8 * c8);
#pragma unroll
      for (int j = 0; j < 8; ++j) a0[j] += bf2f(v0[j]);
    }
    float* dst = out + (size_t)u * DD + 8 * c8;
    float4 o0, o1;
    o0.x = a0[0] + a1[0] + a2[0] + a3[0];
    o0.y = a0[1] + a1[1] + a2[1] + a3[1];
    o0.z = a0[2] + a1[2] + a2[2] + a3[2];
    o0.w = a0[3] + a1[3] + a2[3] + a3[3];
    o1.x = a0[4] + a1[4] + a2[4] + a3[4];
    o1.y = a0[5] + a1[5] + a2[5] + a3[5];
    o1.z = a0[6] + a1[6] + a2[6] + a3[6];
    o1.w = a0[7] + a1[7] + a2[7] + a3[7];
    *(float4*)dst = o0;
    *(float4*)(dst + 4) = o1;
  }
}

// ---------------------------------------------------------------------------
// FC kernel (in-place on d_out): row -> gelu(row*ci) @ W.T + b, 16 rows/wave.
// ---------------------------------------------------------------------------
__global__ __launch_bounds__(256) void gcmc_fc(
    float* __restrict__ out,
    const float* __restrict__ user_ci, const float* __restrict__ movie_ci,
    const float* __restrict__ ufc_w, const float* __restrict__ ufc_b,
    const float* __restrict__ ifc_w, const float* __restrict__ ifc_b)
{
  const int wt   = blockIdx.x * 4 + (threadIdx.x >> 6);
  const int lane = threadIdx.x & 63;
  const int c    = lane & 15;
  const int kr   = lane >> 4;
  const bool isU = wt < (NU / 16);
  float* base        = isU ? out : out + (size_t)NU * DD;
  const float* ci    = isU ? user_ci : movie_ci;
  const float* W     = isU ? ufc_w : ifc_w;
  const float* bias  = isU ? ufc_b : ifc_b;
  const int row0 = (isU ? wt : wt - (NU / 16)) * 16;

  bf16x8 B[4][2];
#pragma unroll
  for (int t = 0; t < 4; ++t)
#pragma unroll
    for (int s = 0; s < 2; ++s)
      B[t][s] = cvt8(W + (size_t)(4 * c + t) * DD + s * 32 + kr * 8);

  const float civ = ci[row0 + c];
  const float* arow = base + (size_t)(row0 + c) * DD + kr * 8;

  bf16x8 A0, A1;
  {
    const float4 a = *(const float4*)arow;
    const float4 b = *(const float4*)(arow + 4);
    const float4 a2 = *(const float4*)(arow + 32);
    const float4 b2 = *(const float4*)(arow + 36);
    A0[0] = f2bf(gelu(a.x * civ));  A0[1] = f2bf(gelu(a.y * civ));
    A0[2] = f2bf(gelu(a.z * civ));  A0[3] = f2bf(gelu(a.w * civ));
    A0[4] = f2bf(gelu(b.x * civ));  A0[5] = f2bf(gelu(b.y * civ));
    A0[6] = f2bf(gelu(b.z * civ));  A0[7] = f2bf(gelu(b.w * civ));
    A1[0] = f2bf(gelu(a2.x * civ)); A1[1] = f2bf(gelu(a2.y * civ));
    A1[2] = f2bf(gelu(a2.z * civ)); A1[3] = f2bf(gelu(a2.w * civ));
    A1[4] = f2bf(gelu(b2.x * civ)); A1[5] = f2bf(gelu(b2.y * civ));
    A1[6] = f2bf(gelu(b2.z * civ)); A1[7] = f2bf(gelu(b2.w * civ));
  }

  f32x4 z4 = {0.f, 0.f, 0.f, 0.f};
  f32x4 C[4];
#pragma unroll
  for (int t = 0; t < 4; ++t) {
    C[t] = z4;
    C[t] = __builtin_amdgcn_mfma_f32_16x16x32_bf16(A0, B[t][0], C[t], 0, 0, 0);
    C[t] = __builtin_amdgcn_mfma_f32_16x16x32_bf16(A1, B[t][1], C[t], 0, 0, 0);
  }

  const float4 b4 = *(const float4*)(bias + 4 * c);
#pragma unroll
  for (int q = 0; q < 4; ++q) {
    const int row = row0 + kr * 4 + q;
    float4 o;
    o.x = C[0][q] + b4.x; o.y = C[1][q] + b4.y;
    o.z = C[2][q] + b4.z; o.w = C[3][q] + b4.w;
    *(float4*)(base + (size_t)row * DD + 4 * c) = o;
  }
}

extern "C" void kernel_launch(void* const* d_in, const int* in_sizes, int n_in,
                              void* d_out, int out_size, void* d_ws, size_t ws_size,
                              hipStream_t stream) {
  const int*   edges_u  = (const int*)  d_in[0];
  const int*   edges_m  = (const int*)  d_in[1];
  const float* rfeat    = (const float*)d_in[2];
  const float* W_user   = (const float*)d_in[3];
  const float* W_movie  = (const float*)d_in[4];
  const float* ps_u     = (const float*)d_in[5];
  const float* rs_u     = (const float*)d_in[6];
  const float* rw_u     = (const float*)d_in[7];
  const float* ps_m     = (const float*)d_in[8];
  const float* rs_m     = (const float*)d_in[9];
  const float* rw_m     = (const float*)d_in[10];
  const float* user_cj  = (const float*)d_in[11];
  const float* user_ci  = (const float*)d_in[12];
  const float* movie_cj = (const float*)d_in[13];
  const float* movie_ci = (const float*)d_in[14];
  const float* ufc_w    = (const float*)d_in[15];
  const float* ufc_b    = (const float*)d_in[16];
  const float* ifc_w    = (const float*)d_in[17];
  const float* ifc_b    = (const float*)d_in[18];

  float* out = (float*)d_out;

  // ---- workspace layout ----
  char* ws = (char*)d_ws;
  size_t o = 0;
  auto alloc = [&](size_t bytes) { char* p = ws + o; o += (bytes + 255) & ~(size_t)255; return p; };
  int*   cnt    = (int*)  alloc(sizeof(int) * NNODE);
  int*   off    = (int*)  alloc(sizeof(int) * (NNODE + 1));
  int*   bsum   = (int*)  alloc(sizeof(int) * NCHUNK);
  int*   bpre   = (int*)  alloc(sizeof(int) * NCHUNK);
  int*   rank_m = (int*)  alloc(sizeof(int) * NE);
  int*   rank_u = (int*)  alloc(sizeof(int) * NE);
  short* msg    = (short*)alloc(sizeof(short) * (size_t)2 * NE * DD);   // 512 MB
  (void)ws_size;

  hipMemsetAsync(cnt, 0, sizeof(int) * NNODE, stream);
  rank0_k<<<(NE / 4 + 255) / 256, 256, 0, stream>>>(edges_u, edges_m, cnt, rank_m, rank_u);
  scan_p1<<<NCHUNK, 256, 0, stream>>>(cnt, bsum);
  scan_p2<<<1, 1024, 0, stream>>>(bsum, bpre);
  scan_p3<<<NCHUNK, 256, 0, stream>>>(cnt, bpre, off);

  dim3 g1((NTILE / 8 + 3) / 4, RR);   // (782, 5)
  gcmc_main<<<g1, 256, 0, stream>>>(edges_u, edges_m, rfeat, W_user, W_movie,
                                    ps_u, rs_u, rw_u, ps_m, rs_m, rw_m,
                                    user_cj, movie_cj, rank_m, rank_u, off, msg);

  gather_k<<<GM_BLOCKS + GU_BLOCKS, 256, 0, stream>>>(off, msg, out);

  gcmc_fc<<<(NNODE / 16) / 4, 256, 0, stream>>>(out, user_ci, movie_ci,
                                                ufc_w, ufc_b, ifc_w, ifc_b);
}